// Round 1
// baseline (87.913 us; speedup 1.0000x reference)
//
#include <hip/hip_runtime.h>

// FALCON ObjectSomeValuesFrom forward, product t-norm.
// Key identity: r_fs[i,j]*c_fs[j] = sigmoid(row_i+col_j+b)*sigmoid(cw+col_j+b)
// is monotone increasing in col_j  =>  max over j is at argmax col_j for ALL i.
// So: out[i] = sigmoid(rowdot_i + rw + colmax + b) * sigmoid(cw + colmax + b).

#define N_NAMED 8000
#define ANON_E  192
#define N_ALL   8192
#define D       128

// order-preserving float<->uint encoding for atomicMax over signed floats;
// 0 is below every real float's encoding (enc(-inf)=0x007FFFFF), so
// memset(0) is a valid identity.
__device__ __forceinline__ unsigned enc_f(float x) {
    unsigned u = __float_as_uint(x);
    return (u & 0x80000000u) ? ~u : (u | 0x80000000u);
}
__device__ __forceinline__ float dec_f(unsigned u) {
    unsigned v = (u & 0x80000000u) ? (u & 0x7fffffffu) : ~u;
    return __uint_as_float(v);
}

// K1: for each row i of e_all = [e_table; anon_e]:
//   rowdot[i] = dot(e_all[i], w_l)  -> d_out[i]
//   col_i     = dot(e_all[i], w_r)  -> block max -> atomicMax ws[0]
// One row per 32-lane group (float4/lane covers the 128-float row).
__global__ __launch_bounds__(256) void k_dots(
    const float* __restrict__ anon_e, const float* __restrict__ e_table,
    const float* __restrict__ fc0_w, float* __restrict__ rowdot,
    unsigned* __restrict__ colmax_enc)
{
    const int tid = threadIdx.x;
    const int g   = tid >> 5;          // group 0..7
    const int l   = tid & 31;          // lane within group
    const int row = blockIdx.x * 8 + g;

    const float4* rp = (row < N_NAMED)
        ? (const float4*)(e_table + (size_t)row * D)
        : (const float4*)(anon_e + (size_t)(row - N_NAMED) * D);

    float4 e  = rp[l];
    float4 wl = ((const float4*)fc0_w)[l];        // w_l[4l..4l+3]
    float4 wr = ((const float4*)fc0_w)[32 + l];   // w_r[4l..4l+3]

    float dl = e.x*wl.x + e.y*wl.y + e.z*wl.z + e.w*wl.w;
    float dr = e.x*wr.x + e.y*wr.y + e.z*wr.z + e.w*wr.w;

    // reduce within the 32-lane group (xor masks <32 stay inside each half)
    #pragma unroll
    for (int off = 16; off >= 1; off >>= 1) {
        dl += __shfl_xor(dl, off, 64);
        dr += __shfl_xor(dr, off, 64);
    }

    __shared__ float scol[8];
    if (l == 0) { rowdot[row] = dl; scol[g] = dr; }
    __syncthreads();
    if (tid == 0) {
        float m = scol[0];
        #pragma unroll
        for (int i = 1; i < 8; i++) m = fmaxf(m, scol[i]);
        atomicMax(colmax_enc, enc_f(m));
    }
}

// K2: out[i] = sigmoid(rowdot_i + rw + colmax + b) * sigmoid(cw + colmax + b)
// cw/rw are wave-uniform 128-dots over cached tables — recompute per thread.
__global__ __launch_bounds__(256) void k_final(
    const float* __restrict__ c_table, const float* __restrict__ r_table,
    const float* __restrict__ fc0_w, const float* __restrict__ fc0_b,
    const int* __restrict__ c_id, const int* __restrict__ r_id,
    const unsigned* __restrict__ colmax_enc, float* __restrict__ out)
{
    const int i = blockIdx.x * 256 + threadIdx.x;
    const int cid = c_id[0], rid = r_id[0];
    const float b = fc0_b[0];
    const float colmax = dec_f(colmax_enc[0]);

    const float* cp = c_table + (size_t)cid * D;
    const float* rp = r_table + (size_t)rid * D;
    float cw = 0.f, rw = 0.f;
    #pragma unroll 8
    for (int t = 0; t < D; t++) {
        float w = fc0_w[t];            // w_l
        cw = fmaf(cp[t], w, cw);
        rw = fmaf(rp[t], w, rw);
    }

    float rowdot = out[i];
    float a1 = rowdot + rw + colmax + b;
    float a2 = cw + colmax + b;
    float s1 = 1.f / (1.f + __expf(-a1));
    float s2 = 1.f / (1.f + __expf(-a2));
    out[i] = s1 * s2;
}

extern "C" void kernel_launch(void* const* d_in, const int* in_sizes, int n_in,
                              void* d_out, int out_size, void* d_ws, size_t ws_size,
                              hipStream_t stream) {
    const float* anon_e  = (const float*)d_in[0];
    const float* e_table = (const float*)d_in[1];
    const float* c_table = (const float*)d_in[2];
    const float* r_table = (const float*)d_in[3];
    const float* fc0_w   = (const float*)d_in[4];
    const float* fc0_b   = (const float*)d_in[5];
    const int*   c_id    = (const int*)d_in[6];
    const int*   r_id    = (const int*)d_in[7];
    float*    out = (float*)d_out;
    unsigned* ws  = (unsigned*)d_ws;

    hipMemsetAsync(ws, 0, sizeof(unsigned), stream);           // atomicMax identity
    k_dots<<<N_ALL / 8, 256, 0, stream>>>(anon_e, e_table, fc0_w, out, ws);
    k_final<<<N_ALL / 256, 256, 0, stream>>>(c_table, r_table, fc0_w, fc0_b,
                                             c_id, r_id, ws, out);
}

// Round 2
// 76.122 us; speedup vs baseline: 1.1549x; 1.1549x over previous
//
#include <hip/hip_runtime.h>

// FALCON ObjectSomeValuesFrom forward, product t-norm.
// Identity: r_fs[i,j]*c_fs[j] = sigmoid(row_i+col_j+b)*sigmoid(cw+col_j+b) is
// strictly increasing in col_j => argmax_j is argmax col_j, same for all i.
//   out[i] = sigmoid(rowdot_i + rw + colmax + b) * sigmoid(cw + colmax + b)
// K1: per-row dots (rowdot -> d_out) + per-block col-max -> ws[blockIdx]
//     (own-slot plain store: no atomic, no init dispatch needed).
// K2: each block reduces the 1024 partial maxima (4 KB, L2-hit), computes the
//     uniform cw/rw dots, applies the two sigmoids elementwise.

#define N_NAMED 8000
#define N_ALL   8192
#define D       128
#define K1_BLOCKS (N_ALL / 8)   // 1024 blocks, 8 rows/block

__global__ __launch_bounds__(256) void k_dots(
    const float* __restrict__ anon_e, const float* __restrict__ e_table,
    const float* __restrict__ fc0_w, float* __restrict__ rowdot,
    float* __restrict__ colmax_part)
{
    const int tid = threadIdx.x;
    const int g   = tid >> 5;          // 32-lane group 0..7
    const int l   = tid & 31;
    const int row = blockIdx.x * 8 + g;

    const float4* rp = (row < N_NAMED)
        ? (const float4*)(e_table + (size_t)row * D)
        : (const float4*)(anon_e + (size_t)(row - N_NAMED) * D);

    float4 e  = rp[l];
    float4 wl = ((const float4*)fc0_w)[l];        // w_l chunk
    float4 wr = ((const float4*)fc0_w)[32 + l];   // w_r chunk

    float dl = e.x*wl.x + e.y*wl.y + e.z*wl.z + e.w*wl.w;
    float dr = e.x*wr.x + e.y*wr.y + e.z*wr.z + e.w*wr.w;

    #pragma unroll
    for (int off = 16; off >= 1; off >>= 1) {   // xor<32: stays in 32-lane group
        dl += __shfl_xor(dl, off, 64);
        dr += __shfl_xor(dr, off, 64);
    }

    __shared__ float scol[8];
    if (l == 0) { rowdot[row] = dl; scol[g] = dr; }
    __syncthreads();
    if (tid == 0) {
        float m = scol[0];
        #pragma unroll
        for (int i = 1; i < 8; i++) m = fmaxf(m, scol[i]);
        colmax_part[blockIdx.x] = m;   // own slot — no init, no atomic
    }
}

__global__ __launch_bounds__(256) void k_final(
    const float* __restrict__ c_table, const float* __restrict__ r_table,
    const float* __restrict__ fc0_w, const float* __restrict__ fc0_b,
    const int* __restrict__ c_id, const int* __restrict__ r_id,
    const float* __restrict__ colmax_part, float* __restrict__ out)
{
    const int tid = threadIdx.x;
    const int i   = blockIdx.x * 256 + tid;

    // block-local reduction of the 1024 partial maxima (L2-resident, 4 KB)
    float m = colmax_part[tid];
    m = fmaxf(m, colmax_part[tid + 256]);
    m = fmaxf(m, colmax_part[tid + 512]);
    m = fmaxf(m, colmax_part[tid + 768]);
    #pragma unroll
    for (int off = 32; off >= 1; off >>= 1)
        m = fmaxf(m, __shfl_xor(m, off, 64));

    __shared__ float swm[4];
    __shared__ float smax;
    if ((tid & 63) == 0) swm[tid >> 6] = m;
    __syncthreads();
    if (tid == 0)
        smax = fmaxf(fmaxf(swm[0], swm[1]), fmaxf(swm[2], swm[3]));
    __syncthreads();
    const float colmax = smax;

    const float b = fc0_b[0];
    const float* cp = c_table + (size_t)c_id[0] * D;
    const float* rp = r_table + (size_t)r_id[0] * D;
    float cw = 0.f, rw = 0.f;
    #pragma unroll 8
    for (int t = 0; t < D; t++) {
        float w = fc0_w[t];            // w_l
        cw = fmaf(cp[t], w, cw);
        rw = fmaf(rp[t], w, rw);
    }

    float a1 = out[i] + rw + colmax + b;
    float a2 = cw + colmax + b;
    float s1 = 1.f / (1.f + __expf(-a1));
    float s2 = 1.f / (1.f + __expf(-a2));
    out[i] = s1 * s2;
}

extern "C" void kernel_launch(void* const* d_in, const int* in_sizes, int n_in,
                              void* d_out, int out_size, void* d_ws, size_t ws_size,
                              hipStream_t stream) {
    const float* anon_e  = (const float*)d_in[0];
    const float* e_table = (const float*)d_in[1];
    const float* c_table = (const float*)d_in[2];
    const float* r_table = (const float*)d_in[3];
    const float* fc0_w   = (const float*)d_in[4];
    const float* fc0_b   = (const float*)d_in[5];
    const int*   c_id    = (const int*)d_in[6];
    const int*   r_id    = (const int*)d_in[7];
    float* out = (float*)d_out;
    float* ws  = (float*)d_ws;   // 1024 partial col-maxima

    k_dots<<<K1_BLOCKS, 256, 0, stream>>>(anon_e, e_table, fc0_w, out, ws);
    k_final<<<N_ALL / 256, 256, 0, stream>>>(c_table, r_table, fc0_w, fc0_b,
                                             c_id, r_id, ws, out);
}